// Round 7
// baseline (509.910 us; speedup 1.0000x reference)
//
#include <hip/hip_runtime.h>
#include <hip/hip_bf16.h>

// MultiHeadAttention fwd: B=2 S=2048 D=2048 H=16 DH=128, causal, fp32 in/out.
// R7: GEMM inner loop -> deep pipeline (m201-style): fragment double-buffering
//     (ds_reads for phase p+1 issued during phase p, counted lgkmcnt), waits
//     moved to phase-END before the barrier (2-phase ~1900cyc prefetch depth >
//     HBM latency), 1 barrier/phase (2/tile vs R6's 4). Tiles/grid unchanged
//     (QKV 256x192 grid 512 = 2.0 rounds; OP 256x128 grid 256 = 1.0).
// Workspace layout (bytes), total 117,440,512:
//   WQKV 0        : 3*D*D*2 = 25165824   (wq;wk;wv rows, bf16)
//   WO   25165824 : D*D*2   = 8388608
//   XB   33554432 : M*D*2   = 16777216   (x bf16; ALIASED later by attn-out)
//   Qb   50331648 : 16777216             ([B,H,S,DH] bf16, pre-scaled 1/sqrt(DH))
//   Kb   67108864 : 16777216
//   VT  100663296 : 16777216             ([B,H,DH,S] bf16, written by QKV gemm)

using u16 = unsigned short;
typedef float  f32x4  __attribute__((ext_vector_type(4)));
typedef short  short8 __attribute__((ext_vector_type(8)));

#define DEV __device__ __forceinline__

constexpr int Bc = 2, Sc = 2048, Dc = 2048, Hc = 16, DHc = 128, Mc = 4096, Kc = 2048;
constexpr float RSCALE = 0.08838834764831845f;   // 1/sqrt(128)
constexpr float L2E    = 1.44269504088896341f;

DEV u16 f2bf(float f) { __bf16 h = (__bf16)f; return __builtin_bit_cast(u16, h); }

DEV void gload_lds16(const void* gsrc, void* lds) {
  __builtin_amdgcn_global_load_lds(
      (const __attribute__((address_space(1))) unsigned int*)gsrc,
      (__attribute__((address_space(3))) unsigned int*)lds, 16, 0, 0);
}

// ---------------- fp32 -> bf16 cast, all 5 tensors in one launch ----------
__global__ void cast_all(const float* __restrict__ x, const float* __restrict__ wq,
                         const float* __restrict__ wk, const float* __restrict__ wv,
                         const float* __restrict__ wo, u16* __restrict__ XB,
                         u16* __restrict__ WQKV, u16* __restrict__ WOb) {
  const int i = blockIdx.x * blockDim.x + threadIdx.x;   // float4 index, 6291456 total
  const float4* src;
  u16* dst;
  if (i < 2097152)      { src = (const float4*)x  + i;             dst = XB   + (size_t)i * 4; }
  else if (i < 3145728) { src = (const float4*)wq + (i - 2097152); dst = WQKV + (size_t)(i - 2097152) * 4; }
  else if (i < 4194304) { src = (const float4*)wk + (i - 3145728); dst = WQKV + 4194304 + (size_t)(i - 3145728) * 4; }
  else if (i < 5242880) { src = (const float4*)wv + (i - 4194304); dst = WQKV + 8388608 + (size_t)(i - 4194304) * 4; }
  else                  { src = (const float4*)wo + (i - 5242880); dst = WOb  + (size_t)(i - 5242880) * 4; }
  float4 v = *src;
  u16 o0 = f2bf(v.x), o1 = f2bf(v.y), o2 = f2bf(v.z), o3 = f2bf(v.w);
  dst[0] = o0; dst[1] = o1; dst[2] = o2; dst[3] = o3;
}

// ---------------- GEMM: C[m,n] = sum_k A[m,k]*W[n,k], bf16, BM=256 ----------
// 512 thr = 8 waves (2M x 4N), wave-tile 128 x (16*FR). BK=64, dbuf LDS.
// 2 phases/K-tile (24*FR/3... = 4*FR*2 MFMA each), frag-dbuf deep pipeline:
//
//   ph0(u): ds_read aH1 frags (buf c)          [8 reads, for ph1(u)]
//           stage Ah1(u+1) -> buf c^1          [2 gloads]
//           lgkmcnt(8)  (drains ph1(u-1)'s 2FR+8 reads = frags for THIS mma)
//           mma(h0): aH0 x bCur
//           vmcnt(2)    (B,Ah0(u+1), staged ph1(u-1), landed -> ph1's reads)
//           s_barrier
//   ph1(u): ds_read bNxt + aH0 frags (buf c^1) [2FR+8 reads, for ph0(u+1)]
//           stage B(u+2),Ah0(u+2) -> buf c     [LB+2 gloads]
//           lgkmcnt(2FR+8) (drains ph0(u)'s 8 aH1 reads)
//           mma(h1): aH1 x bCur
//           vmcnt(LB+2) (Ah1(u+1), staged ph0(u), landed -> ph0(u+1)'s reads)
//           s_barrier
//
// Legality (each stage-overwrite >= 1 barrier after region's reads DRAINED):
//   B(c)/Ah0(c): read-issued ph1(u-1), drained at ph0(u)'s lgkmcnt(8) (< its
//     barrier); overwritten by ph1(u)'s stage (> that barrier). OK
//   Ah1(c^1): read-issued ph0(u), drained at ph1(u)'s lgkmcnt (< its barrier);
//     overwritten by ph0(u+1)'s stage (> that barrier). OK
// Cross-wave publication (vmcnt is per-wave, so each wait precedes a barrier
// and the dependent ds_read follows it):
//   Ah1(u) read at ph0(u): staged ph0(u-1); end-ph1(u-1) vmcnt(LB+2)
//     [outstanding = Ah1(u):2 + B,Ah0(u+1):LB+2] drains it; barrier. OK
//   B,Ah0(u+1) read at ph1(u): staged ph1(u-1); end-ph0(u) vmcnt(2)
//     [outstanding = B,Ah0(u+1):LB+2 + Ah1(u+1):2] drains it; barrier. OK
// Effective prefetch distance: stage (before mma of its phase) -> wait (after
// next phase's mma) ~ 2 MFMA phases ~ 1900 cyc > HBM-miss latency.
// Tails: ph1(NT-1) skips reads -> lgkmcnt(0); end-ph1(NT-2) -> vmcnt(0)
// (stage skipped, count wouldn't cover); end-ph0(NT-1)/end-ph1(NT-1) skip.
// Chunk-XOR swizzle pc = lc ^ (row&7) on source AND ds_read (rule #21;
// R4-R6 measured 0 bank conflicts). All frag rows have row&7 == l15&7.
// EPI 0 (QKV): per-lane section; Q/K scatter (+bias, Q*RSCALE); V transposed
// to VT [B,H,DH,S] packed ushort4. EPI 1: fp32 + bias row-major.
template <int BN, int FR, int EPI>
__global__ __launch_bounds__(512, 2) void gemm2p(
    const u16* __restrict__ A, const u16* __restrict__ W,
    const float* __restrict__ bias0, const float* __restrict__ bias1,
    const float* __restrict__ bias2,
    u16* __restrict__ q_out, u16* __restrict__ k_out, u16* __restrict__ vt_out,
    float* __restrict__ f_out) {
  constexpr int LB = BN / 64;               // B gloads per K-tile
  constexpr int NWR = (EPI == 0) ? 6144 : 2048;
  constexpr int NBX = NWR / BN, NBY = Mc / 256, TOT = NBX * NBY, PX = TOT / 8;
  constexpr int NT = Kc / 64;               // 32, even
  static_assert(BN == FR * 64, "8 waves: 4 N-cols x 16*FR");

  __shared__ u16 lsA[2][256 * 64];
  __shared__ u16 lsB[2][BN * 64];

  const int tid = threadIdx.x;
  const int lane = tid & 63;
  const int w = tid >> 6;
  const int wr = w >> 2, wc = w & 3;
  const int l15 = lane & 15, l4 = lane >> 4;

  // T1 XCD swizzle (TOT % 8 == 0 -> bijective)
  const int id = blockIdx.x;
  const int wg = (id & 7) * PX + (id >> 3);
  const int bx = wg / NBY, by = wg % NBY;
  const int m0 = by * 256, n0 = bx * BN;

  // staging constants
  const int srow = tid >> 3;          // row within 64-row region
  const int spc = tid & 7;            // phys 16B chunk in 128B row
  const int slc = spc ^ (srow & 7);   // source logical chunk (pre-swizzle)

  auto stA = [&](int buf, int t, int j) {   // j = region 0..3 (rows j*64..+63)
    gload_lds16(A + (size_t)(m0 + j * 64 + srow) * Kc + t * 64 + slc * 8,
                &lsA[buf][j * 4096 + tid * 8]);
  };
  auto stB = [&](int buf, int t, int j) {   // j = 0..LB-1
    gload_lds16(W + (size_t)(n0 + j * 64 + srow) * Kc + t * 64 + slc * 8,
                &lsB[buf][j * 4096 + tid * 8]);
  };

  const int pc0 = l4 ^ (l15 & 7);
  const int pc1 = (4 + l4) ^ (l15 & 7);

  f32x4 acc[8][FR] = {};
  short8 aH0[8], aH1[8], bA[FR * 2], bB[FR * 2];

  auto rdA0 = [&](int buf) {
#pragma unroll
    for (int fm = 0; fm < 4; ++fm) {
      const u16* base = &lsA[buf][(wr * 128 + fm * 16 + l15) * 64];
      aH0[fm * 2 + 0] = *(const short8*)(base + pc0 * 8);
      aH0[fm * 2 + 1] = *(const short8*)(base + pc1 * 8);
    }
  };
  auto rdA1 = [&](int buf) {
#pragma unroll
    for (int fm = 0; fm < 4; ++fm) {
      const u16* base = &lsA[buf][(wr * 128 + 64 + fm * 16 + l15) * 64];
      aH1[fm * 2 + 0] = *(const short8*)(base + pc0 * 8);
      aH1[fm * 2 + 1] = *(const short8*)(base + pc1 * 8);
    }
  };
  auto rdB = [&](int buf, short8* bf) {
#pragma unroll
    for (int f = 0; f < FR; ++f) {
      const u16* base = &lsB[buf][(wc * (16 * FR) + f * 16 + l15) * 64];
      bf[f * 2 + 0] = *(const short8*)(base + pc0 * 8);
      bf[f * 2 + 1] = *(const short8*)(base + pc1 * 8);
    }
  };
  auto mma = [&](const short8* af, const short8* bf, int half) {
#pragma unroll
    for (int ks = 0; ks < 2; ++ks)
#pragma unroll
      for (int fm = 0; fm < 4; ++fm)
#pragma unroll
        for (int f = 0; f < FR; ++f)
          acc[half * 4 + fm][f] = __builtin_amdgcn_mfma_f32_16x16x32_bf16(
              af[fm * 2 + ks], bf[f * 2 + ks], acc[half * 4 + fm][f], 0, 0, 0);
  };

  // prologue: tile0 full [B, Ah0, Ah1] + tile1 [B, Ah0]
#pragma unroll
  for (int j = 0; j < LB; ++j) stB(0, 0, j);
  stA(0, 0, 0); stA(0, 0, 2);
  stA(0, 0, 1); stA(0, 0, 3);
#pragma unroll
  for (int j = 0; j < LB; ++j) stB(1, 1, j);
  stA(1, 1, 0); stA(1, 1, 2);
  // drain tile0 entirely (oldest LB+4); leave B,Ah0(1) = LB+2 in flight
  if constexpr (LB == 3) asm volatile("s_waitcnt vmcnt(5)" ::: "memory");
  else                   asm volatile("s_waitcnt vmcnt(4)" ::: "memory");
  __builtin_amdgcn_s_barrier();
  rdB(0, bA);
  rdA0(0);

  auto body = [&](int u, int c, short8* bCur, short8* bNxt) {
    // ---- ph0 (fm half 0 of tile u) ----
    rdA1(c);                                     // frags for ph1(u)
    if (u + 1 < NT) { stA(c ^ 1, u + 1, 1); stA(c ^ 1, u + 1, 3); }
    asm volatile("s_waitcnt lgkmcnt(8)" ::: "memory");   // bCur/aH0 ready
    __builtin_amdgcn_sched_barrier(0);
    __builtin_amdgcn_s_setprio(1); mma(aH0, bCur, 0); __builtin_amdgcn_s_setprio(0);
    if (u + 1 < NT) asm volatile("s_waitcnt vmcnt(2)" ::: "memory");
    __builtin_amdgcn_s_barrier();
    // ---- ph1 (fm half 1 of tile u) ----
    if (u + 1 < NT) { rdB(c ^ 1, bNxt); rdA0(c ^ 1); }   // frags for ph0(u+1)
    if (u + 2 < NT) {
#pragma unroll
      for (int j = 0; j < LB; ++j) stB(c, u + 2, j);
      stA(c, u + 2, 0); stA(c, u + 2, 2);
    }
    if (u + 1 < NT) {
      if constexpr (FR == 3) asm volatile("s_waitcnt lgkmcnt(14)" ::: "memory");
      else                   asm volatile("s_waitcnt lgkmcnt(12)" ::: "memory");
    } else {
      asm volatile("s_waitcnt lgkmcnt(0)" ::: "memory");
    }
    __builtin_amdgcn_sched_barrier(0);
    __builtin_amdgcn_s_setprio(1); mma(aH1, bCur, 1); __builtin_amdgcn_s_setprio(0);
    if (u + 2 < NT) {
      if constexpr (LB == 3) asm volatile("s_waitcnt vmcnt(5)" ::: "memory");
      else                   asm volatile("s_waitcnt vmcnt(4)" ::: "memory");
    } else if (u + 1 < NT) {
      asm volatile("s_waitcnt vmcnt(0)" ::: "memory");
    }
    __builtin_amdgcn_s_barrier();
  };

#pragma unroll 1
  for (int u = 0; u < NT; u += 2) {
    body(u, 0, bA, bB);
    body(u + 1, 1, bB, bA);
  }

  // epilogue; C/D frag layout col=lane&15, row=(lane>>4)*4+reg [m89/m91]
  if constexpr (EPI == 0) {
#pragma unroll
    for (int f = 0; f < FR; ++f) {
      const int n = n0 + wc * (16 * FR) + f * 16 + l15;   // per-lane global col
      const int sec = n >> 11;                            // 0:Q 1:K 2:V (per lane!)
      const int n2 = n & 2047;
      const float bias = sec == 0 ? bias0[n2] : (sec == 1 ? bias1[n2] : bias2[n2]);
      const int h = n2 >> 7, dh = n2 & 127;
#pragma unroll
      for (int fm = 0; fm < 8; ++fm) {
        const int m = m0 + wr * 128 + fm * 16 + l4 * 4;   // +r, r=0..3
        const int bb = m >> 11, s = m & 2047;
        if (sec < 2) {
          const float scl = sec == 0 ? RSCALE : 1.0f;
          u16* dst = sec == 0 ? q_out : k_out;
#pragma unroll
          for (int r = 0; r < 4; ++r)
            dst[((size_t)(bb * Hc + h) * Sc + s + r) * DHc + dh] =
                f2bf((acc[fm][f][r] + bias) * scl);
        } else {
          ushort4 pk;
          pk.x = f2bf(acc[fm][f][0] + bias);
          pk.y = f2bf(acc[fm][f][1] + bias);
          pk.z = f2bf(acc[fm][f][2] + bias);
          pk.w = f2bf(acc[fm][f][3] + bias);
          *(ushort4*)&vt_out[((size_t)(bb * Hc + h) * DHc + dh) * Sc + s] = pk;
        }
      }
    }
  } else {
#pragma unroll
    for (int f = 0; f < FR; ++f) {
      const int n = n0 + wc * (16 * FR) + f * 16 + l15;
      const float bias = bias0[n];
#pragma unroll
      for (int fm = 0; fm < 8; ++fm) {
        const int m = m0 + wr * 128 + fm * 16 + l4 * 4;
#pragma unroll
        for (int r = 0; r < 4; ++r)
          f_out[(size_t)(m + r) * Dc + n] = acc[fm][f][r] + bias;
      }
    }
  }
}

// ---------------- flash attention (causal), R2 structure ----------------
__global__ __launch_bounds__(256) void fattn(
    const u16* __restrict__ Qb, const u16* __restrict__ Kb,
    const u16* __restrict__ VTb, u16* __restrict__ AO) {
  __shared__ u16 lsK[2][64 * 128];
  __shared__ u16 lsV[2][128 * 64];
  __shared__ u16 lsP[4][16 * 64];

  const int tid = threadIdx.x;
  const int lane = tid & 63;
  const int w = tid >> 6;
  const int l15 = lane & 15, l4 = lane >> 4;

  const int id = blockIdx.x;
  const int xcd = id & 7, seq = id >> 3;     // seq 0..63
  const int bh = xcd + 8 * (seq >> 4);       // 4 bh per XCD
  const int pair = seq & 15;

  const int b = bh >> 4, h = bh & 15;
  const size_t kbase = (size_t)bh * Sc * DHc;
  const size_t vbase = (size_t)bh * DHc * Sc;

#pragma unroll 1
  for (int qsel = 0; qsel < 2; ++qsel) {
    const int qt = qsel ? (31 - pair) : pair;
    const int q0 = qt * 64;
    const int ntiles = qt + 1;

    const size_t qbase = ((size_t)bh * Sc + q0 + w * 16 + l15) * DHc;
    short8 qf[4];
#pragma unroll
    for (int ks = 0; ks < 4; ++ks)
      qf[ks] = *(const short8*)&Qb[qbase + ks * 32 + l4 * 8];

    float m_run[4], l_run[4];
#pragma unroll
    for (int r = 0; r < 4; ++r) { m_run[r] = -__builtin_inff(); l_run[r] = 0.f; }
    f32x4 o_acc[8] = {};

    auto stageKV = [&](int sb, int ti) {
      const int kv0 = ti * 64;
#pragma unroll
      for (int c = 0; c < 4; ++c) {
        int p = c * 256 + tid;
        int row = p >> 4, ph = p & 15;
        int lg = (ph & 8) | ((ph ^ row) & 7);
        gload_lds16(Kb + kbase + (size_t)(kv0 + row) * DHc + lg * 8, &lsK[sb][p * 8]);
      }
#pragma unroll
      for (int c = 0; c < 4; ++c) {
        int p = c * 256 + tid;
        int row = p >> 3, ph = p & 7;
        int lg = ph ^ (row & 7);
        gload_lds16(VTb + vbase + (size_t)row * Sc + kv0 + lg * 8, &lsV[sb][p * 8]);
      }
    };

    stageKV(0, 0);
    asm volatile("s_waitcnt vmcnt(0)" ::: "memory");
    __syncthreads();

    int buf = 0;
#pragma unroll 1
    for (int ti = 0; ti < ntiles; ++ti) {
      const int kv0 = ti * 64;
      if (ti + 1 < ntiles) stageKV(buf ^ 1, ti + 1);

      f32x4 s[4] = {};
      __builtin_amdgcn_s_setprio(1);
#pragma unroll
      for (int nf = 0; nf < 4; ++nf) {
        int row = nf * 16 + l15;
#pragma unroll
        for (int ks = 0; ks < 4; ++ks) {
          int lg = ks * 4 + l4;
          int pc = (lg & 8) | ((lg ^ row) & 7);
          short8 kf = *(const short8*)&lsK[buf][row * 128 + pc * 8];
          s[nf] = __builtin_amdgcn_mfma_f32_16x16x32_bf16(qf[ks], kf, s[nf], 0, 0, 0);
        }
      }
      __builtin_amdgcn_s_setprio(0);

      if (kv0 == q0) {
#pragma unroll
        for (int nf = 0; nf < 4; ++nf) {
          int kc = nf * 16 + l15;
#pragma unroll
          for (int r = 0; r < 4; ++r)
            if (kc > w * 16 + l4 * 4 + r) s[nf][r] = -__builtin_inff();
        }
      }
      float alpha[4];
#pragma unroll
      for (int r = 0; r < 4; ++r) {
        float mx = fmaxf(fmaxf(s[0][r], s[1][r]), fmaxf(s[2][r], s[3][r]));
        mx = fmaxf(mx, __shfl_xor(mx, 1));
        mx = fmaxf(mx, __shfl_xor(mx, 2));
        mx = fmaxf(mx, __shfl_xor(mx, 4));
        mx = fmaxf(mx, __shfl_xor(mx, 8));
        float mnew = fmaxf(m_run[r], mx);
        alpha[r] = __builtin_amdgcn_exp2f((m_run[r] - mnew) * L2E);
        m_run[r] = mnew;
      }
#pragma unroll
      for (int nf = 0; nf < 4; ++nf)
#pragma unroll
        for (int r = 0; r < 4; ++r)
          s[nf][r] = __builtin_amdgcn_exp2f((s[nf][r] - m_run[r]) * L2E);
#pragma unroll
      for (int r = 0; r < 4; ++r) {
        float sm = s[0][r] + s[1][r] + s[2][r] + s[3][r];
        sm += __shfl_xor(sm, 1);
        sm += __shfl_xor(sm, 2);
        sm += __shfl_xor(sm, 4);
        sm += __shfl_xor(sm, 8);
        l_run[r] = l_run[r] * alpha[r] + sm;
      }
#pragma unroll
      for (int nf2 = 0; nf2 < 8; ++nf2)
#pragma unroll
        for (int r = 0; r < 4; ++r) o_acc[nf2][r] *= alpha[r];

#pragma unroll
      for (int nf = 0; nf < 4; ++nf)
#pragma unroll
        for (int r = 0; r < 4; ++r) {
          int rif = l4 * 4 + r;
          int kc = nf * 16 + l15;
          int pc = (kc >> 3) ^ (rif & 7);
          lsP[w][rif * 64 + pc * 8 + (kc & 7)] = f2bf(s[nf][r]);
        }
      asm volatile("s_waitcnt lgkmcnt(0)" ::: "memory");

      __builtin_amdgcn_s_setprio(1);
#pragma unroll
      for (int ks = 0; ks < 2; ++ks) {
        int pc = (ks * 4 + l4) ^ (l15 & 7);
        short8 pa = *(const short8*)&lsP[w][l15 * 64 + pc * 8];
#pragma unroll
        for (int nf2 = 0; nf2 < 8; ++nf2) {
          int vrow = nf2 * 16 + l15;
          int vpc = (ks * 4 + l4) ^ (vrow & 7);
          short8 vb = *(const short8*)&lsV[buf][vrow * 64 + vpc * 8];
          o_acc[nf2] = __builtin_amdgcn_mfma_f32_16x16x32_bf16(pa, vb, o_acc[nf2], 0, 0, 0);
        }
      }
      __builtin_amdgcn_s_setprio(0);

      asm volatile("s_waitcnt vmcnt(0)" ::: "memory");
      __syncthreads();
      buf ^= 1;
    }

#pragma unroll
    for (int nf2 = 0; nf2 < 8; ++nf2)
#pragma unroll
      for (int r = 0; r < 4; ++r) {
        int qr = q0 + w * 16 + l4 * 4 + r;
        float ov = o_acc[nf2][r] / l_run[r];
        AO[((size_t)(b * Sc + qr)) * Dc + h * DHc + nf2 * 16 + l15] = f2bf(ov);
      }
    __syncthreads();
  }
}

// ---------------- launch ----------------
extern "C" void kernel_launch(void* const* d_in, const int* in_sizes, int n_in,
                              void* d_out, int out_size, void* d_ws, size_t ws_size,
                              hipStream_t stream) {
  const float* x  = (const float*)d_in[0];
  // d_in[1] = mask (bool) — causal, known statically; unused
  const float* wq = (const float*)d_in[2];
  const float* bq = (const float*)d_in[3];
  const float* wk = (const float*)d_in[4];
  const float* bk = (const float*)d_in[5];
  const float* wv = (const float*)d_in[6];
  const float* bv = (const float*)d_in[7];
  const float* wo = (const float*)d_in[8];
  const float* bo = (const float*)d_in[9];
  float* out = (float*)d_out;

  char* ws = (char*)d_ws;
  u16* WQKV = (u16*)(ws + 0);
  u16* WOb  = (u16*)(ws + 25165824);
  u16* XB   = (u16*)(ws + 33554432);
  u16* Qb   = (u16*)(ws + 50331648);
  u16* Kb   = (u16*)(ws + 67108864);
  u16* VTb  = (u16*)(ws + 100663296);
  u16* AO   = XB;   // x_bf16 dead after QKV gemm; reuse for attention output

  cast_all<<<dim3(24576), dim3(256), 0, stream>>>(x, wq, wk, wv, wo, XB, WQKV, WOb);
  gemm2p<192, 3, 0><<<dim3(512), dim3(512), 0, stream>>>(
      XB, WQKV, bq, bk, bv, Qb, Kb, VTb, nullptr);
  fattn<<<dim3(512), dim3(256), 0, stream>>>(Qb, Kb, VTb, AO);
  gemm2p<128, 2, 1><<<dim3(256), dim3(512), 0, stream>>>(
      AO, WOb, bo, nullptr, nullptr, nullptr, nullptr, nullptr, out);
}